// Round 9
// baseline (327.059 us; speedup 1.0000x reference)
//
#include <hip/hip_runtime.h>
#include <hip/hip_bf16.h>
#include <math.h>

typedef __hip_bfloat16 bf16;
#define DEV __device__ __forceinline__
DEV float silu_f(float x) { return x / (1.0f + __expf(-x)); }
DEV float toF(bf16 x) { return __bfloat162float(x); }
DEV void storeF(float* p, float v) { *p = v; }
DEV void storeF(bf16* p, float v) { *p = __float2bfloat16(v); }

constexpr int Bc = 8, Nc = 256, BNc = 2048, Ec = 16384;
constexpr int Hc = 256, NHc = 8, HDc = 32, VDc = 8;

typedef __attribute__((ext_vector_type(8))) short short8;
typedef __attribute__((ext_vector_type(4))) float floatx4;
union sh8 { short8 v; bf16 x[8]; };

DEV void async_copy16(const void* g, void* l) {
  __builtin_amdgcn_global_load_lds(
      (const __attribute__((address_space(1))) void*)g,
      (__attribute__((address_space(3))) void*)l, 16, 0, 0);
}

// ================= device bodies =================

// ---- CSR build (single block, vectorized int4 loads; R7 straggler fix) ----
DEV void csr_body(const int* __restrict__ ei, int* __restrict__ rowptr,
                  int* __restrict__ eids, int* sm) {
  int* deg = sm;
  int* cur = sm + 2048;
  int* rp  = sm + 4096;
  int* ps  = sm + 6144;
  int t = threadIdx.x;
  for (int i = t; i < 2048; i += 256) { deg[i] = 0; cur[i] = 0; }
  __syncthreads();
#pragma unroll
  for (int rr = 0; rr < 2; ++rr) {
    int4 dv[8];
#pragma unroll
    for (int i = 0; i < 8; ++i)
      dv[i] = *(const int4*)&ei[Ec + ((rr * 8 + i) * 256 + t) * 4];
#pragma unroll
    for (int i = 0; i < 8; ++i) {
      atomicAdd(&deg[dv[i].x], 1); atomicAdd(&deg[dv[i].y], 1);
      atomicAdd(&deg[dv[i].z], 1); atomicAdd(&deg[dv[i].w], 1);
    }
  }
  __syncthreads();
  int loc[8], s = 0;
#pragma unroll
  for (int i = 0; i < 8; ++i) { loc[i] = s; s += deg[t * 8 + i]; }
  ps[t] = s;
  __syncthreads();
  for (int off = 1; off < 256; off <<= 1) {
    int v = (t >= off) ? ps[t - off] : 0;
    __syncthreads();
    ps[t] += v;
    __syncthreads();
  }
  int base = (t == 0) ? 0 : ps[t - 1];
#pragma unroll
  for (int i = 0; i < 8; ++i) {
    rp[t * 8 + i] = base + loc[i];
    rowptr[t * 8 + i] = base + loc[i];
  }
  if (t == 255) rowptr[2048] = Ec;
  __syncthreads();
#pragma unroll
  for (int rr = 0; rr < 2; ++rr) {
    int4 dv[8];
#pragma unroll
    for (int i = 0; i < 8; ++i)
      dv[i] = *(const int4*)&ei[Ec + ((rr * 8 + i) * 256 + t) * 4];
#pragma unroll
    for (int i = 0; i < 8; ++i) {
      int e0 = ((rr * 8 + i) * 256 + t) * 4;
      int p0 = atomicAdd(&cur[dv[i].x], 1); eids[rp[dv[i].x] + p0] = e0;
      int p1 = atomicAdd(&cur[dv[i].y], 1); eids[rp[dv[i].y] + p1] = e0 + 1;
      int p2 = atomicAdd(&cur[dv[i].z], 1); eids[rp[dv[i].z] + p2] = e0 + 2;
      int p3 = atomicAdd(&cur[dv[i].w], 1); eids[rp[dv[i].w] + p3] = e0 + 3;
    }
  }
}

// ---- weight transpose+cvt ----
struct WDesc { const float* in; bf16* out; int K, N; };

DEV void wprep_body(WDesc wd, int by, int bx, float* sm) {
  if (by * 32 >= wd.N) return;
  float (*t)[33] = (float (*)[33])sm;
  int k0 = bx * 32, n0 = by * 32;
  int tx = threadIdx.x & 31, ty = threadIdx.x >> 5;
#pragma unroll
  for (int i = 0; i < 32; i += 8)
    t[ty + i][tx] = wd.in[(size_t)(k0 + ty + i) * wd.N + n0 + tx];
  __syncthreads();
#pragma unroll
  for (int i = 0; i < 32; i += 8)
    wd.out[(size_t)(n0 + ty + i) * wd.K + k0 + tx] = __float2bfloat16(t[tx][ty + i]);
}

// ---- fp32 -> bf16 ----
DEV void cvt_body(const float* __restrict__ in, bf16* __restrict__ out, int blk) {
  int i = (blk * 256 + threadIdx.x) * 4;
  float4 v = *(const float4*)&in[i];
  union { bf16 x[4]; uint2 u; } o;
  o.x[0] = __float2bfloat16(v.x); o.x[1] = __float2bfloat16(v.y);
  o.x[2] = __float2bfloat16(v.z); o.x[3] = __float2bfloat16(v.w);
  *(uint2*)&out[i] = o.u;
}

// ---- LayerNorm ----
DEV void ln_body(const float* __restrict__ x, const float* __restrict__ w,
                 const float* __restrict__ b, bf16* __restrict__ xn,
                 int row, float* sm) {
  int h = threadIdx.x;
  float v = x[(size_t)row * Hc + h];
  sm[h] = v; __syncthreads();
  for (int s = 128; s > 0; s >>= 1) { if (h < s) sm[h] += sm[h + s]; __syncthreads(); }
  float mu = sm[0] * (1.0f / 256.0f);
  __syncthreads();
  float d = v - mu;
  sm[h] = d * d; __syncthreads();
  for (int s = 128; s > 0; s >>= 1) { if (h < s) sm[h] += sm[h + s]; __syncthreads(); }
  float var = sm[0] * (1.0f / 256.0f);
  float r = rsqrtf(var + 1e-5f);
  xn[(size_t)row * Hc + h] = __float2bfloat16(d * r * w[h] + b[h]);
}

// ---- MFMA GEMM tile body ----
template <int ACT, typename TC>
DEV void mgemm_body(const bf16* __restrict__ A, const bf16* __restrict__ Bt,
                    const float* __restrict__ bias, TC* __restrict__ C,
                    int M, int K, int N, int m0, int n0,
                    bf16* Als, bf16* Bls) {
  int tid = threadIdx.x;
  int lane = tid & 63, w = tid >> 6;
  int wm = (w & 1) * 64, wn = (w >> 1) * 64;
  int fm = lane & 15, g = lane >> 4;
  floatx4 acc[4][4] = {};
  for (int k0 = 0; k0 < K; k0 += 32) {
#pragma unroll
    for (int t = 0; t < 2; ++t) {
      int c = t * 256 + w * 64 + lane;
      int r = c >> 2, q = c & 3;
      bf16* ldsA = &Als[(t * 256 + w * 64) * 8 + lane * 8];
      bf16* ldsB = &Bls[(t * 256 + w * 64) * 8 + lane * 8];
      async_copy16(A + (size_t)(m0 + r) * K + k0 + q * 8, ldsA);
      async_copy16(Bt + (size_t)(n0 + r) * K + k0 + q * 8, ldsB);
    }
    __syncthreads();
    short8 af[4], bg[4];
#pragma unroll
    for (int i = 0; i < 4; ++i) {
      af[i] = *(const short8*)&Als[(wm + i * 16 + fm) * 32 + g * 8];
      bg[i] = *(const short8*)&Bls[(wn + i * 16 + fm) * 32 + g * 8];
    }
#pragma unroll
    for (int mi = 0; mi < 4; ++mi)
#pragma unroll
      for (int ni = 0; ni < 4; ++ni)
        acc[mi][ni] = __builtin_amdgcn_mfma_f32_16x16x32_bf16(
            af[mi], bg[ni], acc[mi][ni], 0, 0, 0);
    __syncthreads();
  }
#pragma unroll
  for (int mi = 0; mi < 4; ++mi) {
    int row0 = m0 + wm + mi * 16 + g * 4;
#pragma unroll
    for (int ni = 0; ni < 4; ++ni) {
      int col = n0 + wn + ni * 16 + fm;
      float bv = bias ? bias[col] : 0.0f;
#pragma unroll
      for (int r = 0; r < 4; ++r) {
        float v = acc[mi][ni][r] + bv;
        if (ACT) v = silu_f(v);
        storeF(&C[(size_t)(row0 + r) * N + col], v);
      }
    }
  }
}

// ---- xagg gather (8 nodes/block) ----
DEV void xagg_body(const bf16* __restrict__ vj, const int* __restrict__ rowptr,
                   const int* __restrict__ eids, bf16* __restrict__ xagg, int blk) {
  int node = blk * 8 + (threadIdx.x >> 5);
  int tx = threadIdx.x & 31;
  float acc[8] = {};
  int lo = rowptr[node], hi = rowptr[node + 1];
  for (int i = lo; i < hi; ++i) {
    sh8 vv; vv.v = *(const short8*)&vj[(size_t)eids[i] * 256 + tx * 8];
#pragma unroll
    for (int c = 0; c < 8; ++c) acc[c] += toF(vv.x[c]);
  }
  sh8 o;
#pragma unroll
  for (int c = 0; c < 8; ++c) o.x[c] = __float2bfloat16(acc[c]);
  *(short8*)&xagg[(size_t)node * 256 + tx * 8] = o.v;
}

// ---- df per dst node (CSR): t1 staged in LDS once, t2 gathered per edge ----
DEV void df_node_body(const bf16* __restrict__ vpT, const float* __restrict__ d_ij,
                      const bf16* __restrict__ fW, const int* __restrict__ ei,
                      const int* __restrict__ rowptr, const int* __restrict__ eids,
                      float* __restrict__ out, int node, bf16* lds /*2048 bf16*/) {
  int tid = threadIdx.x, te = tid >> 5, tx = tid & 31;
  // stage t1[vd=te][cols tx*8..] into LDS (exactly 256 threads)
  *(short8*)&lds[te * 256 + tx * 8] =
      *(const short8*)&vpT[((size_t)(node * 8 + te)) * 1024 + 512 + tx * 8];
  __syncthreads();
  int lo = rowptr[node], hi = rowptr[node + 1];
  for (int base = lo; base < hi; base += 8) {
    int idx = base + te;
    if (idx < hi) {
      int e = eids[idx];
      int src = ei[e];
      float4 da = *(const float4*)&d_ij[e * 8];
      float4 db = *(const float4*)&d_ij[e * 8 + 4];
      float dd[8] = {da.x, da.y, da.z, da.w, db.x, db.y, db.z, db.w};
      float S[8] = {}, p1[8] = {}, p2[8] = {};
#pragma unroll
      for (int vd = 0; vd < 8; ++vd) {
        sh8 t1; t1.v = *(const short8*)&lds[vd * 256 + tx * 8];
        sh8 t2; t2.v = *(const short8*)&vpT[((size_t)(src * 8 + vd)) * 1024 + 768 + tx * 8];
#pragma unroll
        for (int c = 0; c < 8; ++c) {
          float a = toF(t1.x[c]), b = toF(t2.x[c]);
          S[c] += a * b; p1[c] += a * dd[vd]; p2[c] += b * dd[vd];
        }
      }
      sh8 fw; fw.v = *(const short8*)&fW[(size_t)e * 256 + tx * 8];
      float o[8];
#pragma unroll
      for (int c = 0; c < 8; ++c) o[c] = toF(fw.x[c]) * (S[c] - p1[c] * p2[c]);
      float* dp = &out[(size_t)e * 256 + tx * 8];
      *(float4*)dp = make_float4(o[0], o[1], o[2], o[3]);
      *(float4*)(dp + 4) = make_float4(o[4], o[5], o[6], o[7]);
    }
  }
}

DEV void dxsum_body(const bf16* __restrict__ vpT, const float* __restrict__ ob,
                    float* __restrict__ out, int blk) {
  int row = blk * 8 + (threadIdx.x >> 5);
  int tx = threadIdx.x & 31;
  float s[8] = {};
#pragma unroll
  for (int vd = 0; vd < 8; ++vd) {
    sh8 vv; vv.v = *(const short8*)&vpT[((size_t)(row * 8 + vd)) * 1024 + tx * 8];
#pragma unroll
    for (int c = 0; c < 8; ++c) s[c] += toF(vv.x[c]);
  }
  float4 o2a = *(const float4*)&ob[(size_t)row * 768 + 256 + tx * 8];
  float4 o2b = *(const float4*)&ob[(size_t)row * 768 + 260 + tx * 8];
  float4 o3a = *(const float4*)&ob[(size_t)row * 768 + 512 + tx * 8];
  float4 o3b = *(const float4*)&ob[(size_t)row * 768 + 516 + tx * 8];
  float o2[8] = {o2a.x, o2a.y, o2a.z, o2a.w, o2b.x, o2b.y, o2b.z, o2b.w};
  float o3[8] = {o3a.x, o3a.y, o3a.z, o3a.w, o3b.x, o3b.y, o3b.z, o3b.w};
  float r[8];
#pragma unroll
  for (int c = 0; c < 8; ++c) r[c] = s[c] * o2[c] + o3[c];
  float* dp = &out[(size_t)row * 256 + tx * 8];
  *(float4*)dp = make_float4(r[0], r[1], r[2], r[3]);
  *(float4*)(dp + 4) = make_float4(r[4], r[5], r[6], r[7]);
}

// ---- dvec: 8 nodes/block, 32 threads/node, vd in registers ----
// s12 read ONCE per edge (was 8x redundant across vd-groups in R8).
DEV void dvec_body(const bf16* __restrict__ vec_bf, const bf16* __restrict__ s12,
                   const float* __restrict__ d_ij, const int* __restrict__ ei,
                   const int* __restrict__ rowptr, const int* __restrict__ eids,
                   const bf16* __restrict__ vpT, const float* __restrict__ ob,
                   float* __restrict__ out, int blk) {
  int tn = threadIdx.x >> 5, tx = threadIdx.x & 31;
  int n = blk * 8 + tn;
  float acc[8][8] = {};
  int lo = rowptr[n], hi = rowptr[n + 1];
  for (int i = lo; i < hi; ++i) {
    int e = eids[i];
    int src = ei[e];
    sh8 s1, s2;
    s1.v = *(const short8*)&s12[(size_t)e * 512 + tx * 8];
    s2.v = *(const short8*)&s12[(size_t)e * 512 + 256 + tx * 8];
    float4 da = *(const float4*)&d_ij[e * 8];
    float4 db = *(const float4*)&d_ij[e * 8 + 4];
    float dd[8] = {da.x, da.y, da.z, da.w, db.x, db.y, db.z, db.w};
#pragma unroll
    for (int vd = 0; vd < 8; ++vd) {
      sh8 vv; vv.v = *(const short8*)&vec_bf[((size_t)(src * 8 + vd)) * 256 + tx * 8];
#pragma unroll
      for (int c = 0; c < 8; ++c)
        acc[vd][c] += toF(vv.x[c]) * toF(s1.x[c]) + toF(s2.x[c]) * dd[vd];
    }
  }
  float4 o1a = *(const float4*)&ob[(size_t)n * 768 + tx * 8];
  float4 o1b = *(const float4*)&ob[(size_t)n * 768 + 4 + tx * 8];
  float o1[8] = {o1a.x, o1a.y, o1a.z, o1a.w, o1b.x, o1b.y, o1b.z, o1b.w};
#pragma unroll
  for (int vd = 0; vd < 8; ++vd) {
    sh8 v3; v3.v = *(const short8*)&vpT[((size_t)(n * 8 + vd)) * 1024 + 256 + tx * 8];
    float r[8];
#pragma unroll
    for (int c = 0; c < 8; ++c) r[c] = toF(v3.x[c]) * o1[c] + acc[vd][c];
    float* dp = &out[((size_t)(n * 8 + vd)) * 256 + tx * 8];
    *(float4*)dp = make_float4(r[0], r[1], r[2], r[3]);
    *(float4*)(dp + 4) = make_float4(r[4], r[5], r[6], r[7]);
  }
}

// ================= fused kernels =================

// ---- stage 1: csr | wprep x11 | cvt2 | ln ----
struct PrepArgs {
  const int* ei; int* rowptr; int* eids;
  WDesc wd[11];
  const float* f_ij; bf16* f_bf;
  const float* vec; bf16* vec_bf;
  const float* x; const float* ln_w; const float* ln_b; bf16* xn;
};

__global__ __launch_bounds__(256) void prep_k(PrepArgs a) {
  __shared__ __align__(16) char smem[25600];
  int blk = blockIdx.x;
  if (blk == 0) { csr_body(a.ei, a.rowptr, a.eids, (int*)smem); return; }
  blk -= 1;
  if (blk < 2112) { wprep_body(a.wd[blk / 192], (blk % 192) / 8, blk % 8, (float*)smem); return; }
  blk -= 2112;
  if (blk < 8192) {
    if (blk < 4096) cvt_body(a.f_ij, a.f_bf, blk);
    else cvt_body(a.vec, a.vec_bf, blk - 4096);
    return;
  }
  blk -= 8192;
  ln_body(a.x, a.ln_w, a.ln_b, a.xn, blk, (float*)smem);
}

// ---- stage 2: qkv GEMM | vpT GEMM ----
struct G2Args {
  const bf16 *xn, *Wqkv, *vecbf, *Wvt;
  bf16 *qkv, *vpT;
};
__global__ __launch_bounds__(256) void gemm2_k(G2Args a) {
  __shared__ __align__(16) char smem[16384];
  bf16* Als = (bf16*)smem; bf16* Bls = (bf16*)(smem + 8192);
  int id = blockIdx.x;
  if (id < 96)
    mgemm_body<0, bf16>(a.xn, a.Wqkv, nullptr, a.qkv, BNc, Hc, 768,
                        (id % 16) * 128, (id / 16) * 128, Als, Bls);
  else {
    id -= 96;
    mgemm_body<0, bf16>(a.vecbf, a.Wvt, nullptr, a.vpT, Ec, Hc, 1024,
                        (id % 128) * 128, (id / 128) * 128, Als, Bls);
  }
}

// ---- stage 3: MFMA attention ----
__global__ __launch_bounds__(256) void attn_mfma_k(
    const bf16* __restrict__ qkv, bf16* __restrict__ ob) {
  constexpr int QS = 768;
  int b = blockIdx.x >> 3, h = blockIdx.x & 7;
  int tid = threadIdx.x, lane = tid & 63, w = tid >> 6;
  int fm = lane & 15, g = lane >> 4;
  __shared__ bf16 Vt[32][264];
  __shared__ bf16 Ps[4][64][72];
  const bf16* qb = qkv + (size_t)b * 256 * QS + h * 32;
  const bf16* kb = qb + 256;
  const bf16* vb = qb + 512;
#pragma unroll
  for (int c = 0; c < 4; ++c) {
    int chunk = c * 256 + tid;
    int j = chunk >> 2, part = chunk & 3;
    sh8 t;
    t.v = *(const short8*)(vb + (size_t)j * QS + part * 8);
#pragma unroll
    for (int i = 0; i < 8; ++i) Vt[part * 8 + i][j] = t.x[i];
  }
  __syncthreads();
  short8 af[4];
#pragma unroll
  for (int mi = 0; mi < 4; ++mi)
    af[mi] = *(const short8*)(qb + (size_t)(w * 64 + mi * 16 + fm) * QS + g * 8);
  floatx4 oacc[4][2] = {};
  for (int jt = 0; jt < 4; ++jt) {
#pragma unroll
    for (int ni = 0; ni < 4; ++ni) {
      short8 bg = *(const short8*)(kb + (size_t)(jt * 64 + ni * 16 + fm) * QS + g * 8);
#pragma unroll
      for (int mi = 0; mi < 4; ++mi) {
        floatx4 z = {0.f, 0.f, 0.f, 0.f};
        floatx4 s = __builtin_amdgcn_mfma_f32_16x16x32_bf16(af[mi], bg, z, 0, 0, 0);
#pragma unroll
        for (int r = 0; r < 4; ++r) {
          float v = silu_f(s[r] * 0.17677669529663687f);
          Ps[w][mi * 16 + g * 4 + r][ni * 16 + fm] = __float2bfloat16(v);
        }
      }
    }
#pragma unroll
    for (int kt = 0; kt < 2; ++kt) {
      short8 bv0 = *(const short8*)&Vt[fm][jt * 64 + kt * 32 + g * 8];
      short8 bv1 = *(const short8*)&Vt[16 + fm][jt * 64 + kt * 32 + g * 8];
#pragma unroll
      for (int mi = 0; mi < 4; ++mi) {
        short8 ap = *(const short8*)&Ps[w][mi * 16 + fm][kt * 32 + g * 8];
        oacc[mi][0] = __builtin_amdgcn_mfma_f32_16x16x32_bf16(ap, bv0, oacc[mi][0], 0, 0, 0);
        oacc[mi][1] = __builtin_amdgcn_mfma_f32_16x16x32_bf16(ap, bv1, oacc[mi][1], 0, 0, 0);
      }
    }
  }
#pragma unroll
  for (int mi = 0; mi < 4; ++mi)
#pragma unroll
    for (int ni = 0; ni < 2; ++ni)
#pragma unroll
      for (int r = 0; r < 4; ++r) {
        int row = w * 64 + mi * 16 + g * 4 + r;
        int d = ni * 16 + fm;
        ob[((size_t)(b * 256 + row)) * 256 + h * 32 + d] =
            __float2bfloat16(oacc[mi][ni][r] * (1.0f / 256.0f));
      }
}

// ---- stage 4: Wao GEMM ----
template <int ACT, typename TC>
__global__ __launch_bounds__(256) void mgemm_k(
    const bf16* __restrict__ A, const bf16* __restrict__ Bt,
    const float* __restrict__ bias, TC* __restrict__ C,
    int M, int K, int N) {
  __shared__ __align__(16) char smem[16384];
  mgemm_body<ACT, TC>(A, Bt, bias, C, M, K, N,
                      blockIdx.x * 128, blockIdx.y * 128,
                      (bf16*)smem, (bf16*)(smem + 8192));
}

// ---- stage 5: dv|fW GEMM + fused vj epilogue ----
__global__ __launch_bounds__(256) void gemm_dvfw_k(
    const bf16* __restrict__ A, const bf16* __restrict__ Bt,
    const float* __restrict__ bdv, const float* __restrict__ bf_,
    const int* __restrict__ ei, const float* __restrict__ r_ij,
    const float* __restrict__ vbuf,
    bf16* __restrict__ vj, bf16* __restrict__ fW) {
  constexpr int K = 256;
  __shared__ __align__(16) char smem[16384];
  bf16* Als = (bf16*)smem; bf16* Bls = (bf16*)(smem + 8192);
  int tid = threadIdx.x;
  int lane = tid & 63, w = tid >> 6;
  int m0 = blockIdx.x * 128, n0 = blockIdx.y * 128;
  int wm = (w & 1) * 64, wn = (w >> 1) * 64;
  int fm = lane & 15, g = lane >> 4;
  floatx4 acc[4][4] = {};
  for (int k0 = 0; k0 < K; k0 += 32) {
#pragma unroll
    for (int t = 0; t < 2; ++t) {
      int c = t * 256 + w * 64 + lane;
      int r = c >> 2, q = c & 3;
      bf16* ldsA = &Als[(t * 256 + w * 64) * 8 + lane * 8];
      bf16* ldsB = &Bls[(t * 256 + w * 64) * 8 + lane * 8];
      async_copy16(A + (size_t)(m0 + r) * K + k0 + q * 8, ldsA);
      async_copy16(Bt + (size_t)(n0 + r) * K + k0 + q * 8, ldsB);
    }
    __syncthreads();
    short8 af[4], bg[4];
#pragma unroll
    for (int i = 0; i < 4; ++i) {
      af[i] = *(const short8*)&Als[(wm + i * 16 + fm) * 32 + g * 8];
      bg[i] = *(const short8*)&Bls[(wn + i * 16 + fm) * 32 + g * 8];
    }
#pragma unroll
    for (int mi = 0; mi < 4; ++mi)
#pragma unroll
      for (int ni = 0; ni < 4; ++ni)
        acc[mi][ni] = __builtin_amdgcn_mfma_f32_16x16x32_bf16(
            af[mi], bg[ni], acc[mi][ni], 0, 0, 0);
    __syncthreads();
  }
  bool isVj = (n0 < 256);
#pragma unroll
  for (int mi = 0; mi < 4; ++mi) {
    int row0 = m0 + wm + mi * 16 + g * 4;
#pragma unroll
    for (int r = 0; r < 4; ++r) {
      int e = row0 + r;
      int src = 0; float cut = 0.f;
      if (isVj) {
        src = ei[e];
        float rr = r_ij[e];
        cut = (rr < 5.0f) ? 0.5f * (cosf(0.6283185307179586f * rr) + 1.0f) : 0.0f;
      }
#pragma unroll
      for (int ni = 0; ni < 4; ++ni) {
        int col = n0 + wn + ni * 16 + fm;
        if (isVj) {
          float v = silu_f(acc[mi][ni][r] + bdv[col]);
          vj[(size_t)e * 256 + col] =
              __float2bfloat16(vbuf[(size_t)src * 256 + col] * cut * v);
        } else {
          float v = silu_f(acc[mi][ni][r] + bf_[col - 256]);
          fW[(size_t)e * 256 + (col - 256)] = __float2bfloat16(v);
        }
      }
    }
  }
}

// ---- stage 6: s12 GEMM | xagg ----
struct S6Args {
  const bf16 *vj, *Ws_t; const float* bs; bf16* s12;
  const int *rowptr, *eids; bf16* xagg;
};
__global__ __launch_bounds__(256) void stage6_k(S6Args a) {
  __shared__ __align__(16) char smem[16384];
  int id = blockIdx.x;
  if (id < 512)
    mgemm_body<1, bf16>(a.vj, a.Ws_t, a.bs, a.s12, Ec, Hc, 512,
                        (id % 128) * 128, (id / 128) * 128,
                        (bf16*)smem, (bf16*)(smem + 8192));
  else
    xagg_body(a.vj, a.rowptr, a.eids, a.xagg, id - 512);
}

// ---- stage 7: Wo GEMM | df (CSR per-node) ----
struct S7Args {
  const bf16 *xagg, *Wo_t; const float* bo; float* obuf;
  const bf16* vpT; const float* d_ij; const bf16* fW;
  const int *ei, *rowptr, *eids; float* out_df;
};
__global__ __launch_bounds__(256) void stage7_k(S7Args a) {
  __shared__ __align__(16) char smem[16384];
  int id = blockIdx.x;
  if (id < 96)
    mgemm_body<0, float>(a.xagg, a.Wo_t, a.bo, a.obuf, BNc, Hc, 768,
                         (id % 16) * 128, (id / 16) * 128,
                         (bf16*)smem, (bf16*)(smem + 8192));
  else
    df_node_body(a.vpT, a.d_ij, a.fW, a.ei, a.rowptr, a.eids,
                 a.out_df, id - 96, (bf16*)smem);
}

// ---- stage 8: dxsum | dvec ----
struct S8Args {
  const bf16* vpT; const float* obuf; float* out_dx;
  const bf16 *vecbf, *s12; const float* d_ij;
  const int *ei, *rowptr, *eids; float* out_dvec;
};
__global__ __launch_bounds__(256) void stage8_k(S8Args a) {
  int id = blockIdx.x;
  if (id < 256)
    dxsum_body(a.vpT, a.obuf, a.out_dx, id);
  else
    dvec_body(a.vecbf, a.s12, a.d_ij, a.ei, a.rowptr, a.eids,
              a.vpT, a.obuf, a.out_dvec, id - 256);
}

extern "C" void kernel_launch(void* const* d_in, const int* in_sizes, int n_in,
                              void* d_out, int out_size, void* d_ws, size_t ws_size,
                              hipStream_t stream) {
  const float* x    = (const float*)d_in[0];
  const float* vec  = (const float*)d_in[1];
  const int*   ei   = (const int*)d_in[2];
  const float* r_ij = (const float*)d_in[3];
  const float* f_ij = (const float*)d_in[4];
  const float* d_ij = (const float*)d_in[5];
  const float* ln_w = (const float*)d_in[7];
  const float* ln_b = (const float*)d_in[8];
  const float* Wq   = (const float*)d_in[9];
  const float* Wk   = (const float*)d_in[10];
  const float* Wv   = (const float*)d_in[11];
  const float* Wao  = (const float*)d_in[12];
  const float* Wvec = (const float*)d_in[13];
  const float* Wdv  = (const float*)d_in[14];
  const float* bdv  = (const float*)d_in[15];
  const float* Ws   = (const float*)d_in[16];
  const float* bs   = (const float*)d_in[17];
  const float* Wo   = (const float*)d_in[18];
  const float* bo   = (const float*)d_in[19];
  const float* Wf   = (const float*)d_in[20];
  const float* bf_  = (const float*)d_in[21];
  const float* Wsrc = (const float*)d_in[22];
  const float* Wtrg = (const float*)d_in[23];

  char* p = (char*)d_ws;
  auto alloc = [&](size_t bytes) {
    char* r = p; p += (bytes + 255) & ~(size_t)255; return r;
  };
  bf16*  xn_bf   = (bf16*)alloc((size_t)BNc * Hc * 2);
  bf16*  qkv_bf  = (bf16*)alloc((size_t)BNc * 3 * Hc * 2);
  bf16*  attn_bf = (bf16*)alloc((size_t)BNc * Hc * 2);
  float* vbuf    = (float*)alloc((size_t)BNc * Hc * 4);
  bf16*  xagg_bf = (bf16*)alloc((size_t)BNc * Hc * 2);
  float* obuf    = (float*)alloc((size_t)BNc * 3 * Hc * 4);
  bf16*  f_bf    = (bf16*)alloc((size_t)Ec * Hc * 2);
  bf16*  vec_bf  = (bf16*)alloc((size_t)BNc * VDc * Hc * 2);
  bf16*  vpT     = (bf16*)alloc((size_t)Ec * 1024 * 2);     // v1|v3|Tt|Ts
  bf16*  vj_bf   = (bf16*)alloc((size_t)Ec * Hc * 2);
  bf16*  s12_bf  = (bf16*)alloc((size_t)Ec * 2 * Hc * 2);
  bf16*  fW_bf   = (bf16*)alloc((size_t)Ec * Hc * 2);
  bf16*  Wqkv_t  = (bf16*)alloc((size_t)3 * Hc * Hc * 2);
  bf16*  Wao_t   = (bf16*)alloc((size_t)Hc * Hc * 2);
  bf16*  Wdvf_t  = (bf16*)alloc((size_t)2 * Hc * Hc * 2);
  bf16*  Wvt_t   = (bf16*)alloc((size_t)4 * Hc * Hc * 2);
  bf16*  Ws_t    = (bf16*)alloc((size_t)2 * Hc * Hc * 2);
  bf16*  Wo_t    = (bf16*)alloc((size_t)3 * Hc * Hc * 2);
  int*   rowptr  = (int*)alloc(2049 * 4);
  int*   eids    = (int*)alloc(Ec * 4);

  float* out_dx   = (float*)d_out;
  float* out_dvec = (float*)d_out + 524288;
  float* out_df   = (float*)d_out + 4718592;

  // stage 1: csr | wprep | cvt2 | ln
  PrepArgs pa;
  pa.ei = ei; pa.rowptr = rowptr; pa.eids = eids;
  pa.wd[0]  = {Wq,   Wqkv_t,           Hc, Hc};
  pa.wd[1]  = {Wk,   Wqkv_t + 65536,   Hc, Hc};
  pa.wd[2]  = {Wv,   Wqkv_t + 131072,  Hc, Hc};
  pa.wd[3]  = {Wao,  Wao_t,            Hc, Hc};
  pa.wd[4]  = {Wdv,  Wdvf_t,           Hc, Hc};
  pa.wd[5]  = {Wf,   Wdvf_t + 65536,   Hc, Hc};
  pa.wd[6]  = {Wvec, Wvt_t,            Hc, 2 * Hc};
  pa.wd[7]  = {Wtrg, Wvt_t + 131072,   Hc, Hc};
  pa.wd[8]  = {Wsrc, Wvt_t + 196608,   Hc, Hc};
  pa.wd[9]  = {Ws,   Ws_t,             Hc, 2 * Hc};
  pa.wd[10] = {Wo,   Wo_t,             Hc, 3 * Hc};
  pa.f_ij = f_ij; pa.f_bf = f_bf; pa.vec = vec; pa.vec_bf = vec_bf;
  pa.x = x; pa.ln_w = ln_w; pa.ln_b = ln_b; pa.xn = xn_bf;
  prep_k<<<12353, 256, 0, stream>>>(pa);

  // stage 2: qkv | vpT GEMMs
  G2Args g2{xn_bf, Wqkv_t, vec_bf, Wvt_t, qkv_bf, vpT};
  gemm2_k<<<1120, 256, 0, stream>>>(g2);

  // stage 3: attention
  attn_mfma_k<<<Bc * NHc, 256, 0, stream>>>(qkv_bf, attn_bf);

  // stage 4: v = attn @ Wao
  mgemm_k<0, float><<<dim3(16, 2), 256, 0, stream>>>(attn_bf, Wao_t, nullptr, vbuf, BNc, Hc, Hc);

  // stage 5: dv|fW GEMM + vj epilogue
  gemm_dvfw_k<<<dim3(128, 4), 256, 0, stream>>>(f_bf, Wdvf_t, bdv, bf_, ei, r_ij,
                                                vbuf, vj_bf, fW_bf);

  // stage 6: s12 GEMM | xagg (512 + 256)
  S6Args s6{vj_bf, Ws_t, bs, s12_bf, rowptr, eids, xagg_bf};
  stage6_k<<<768, 256, 0, stream>>>(s6);

  // stage 7: Wo GEMM | df per-node (96 + 2048)
  S7Args s7{xagg_bf, Wo_t, bo, obuf, vpT, d_ij, fW_bf, ei, rowptr, eids, out_df};
  stage7_k<<<2144, 256, 0, stream>>>(s7);

  // stage 8: dxsum | dvec (256 + 256)
  S8Args s8{vpT, obuf, out_dx, vec_bf, s12_bf, d_ij, ei, rowptr, eids, out_dvec};
  stage8_k<<<512, 256, 0, stream>>>(s8);

  (void)in_sizes; (void)n_in; (void)out_size; (void)ws_size;
}